// Round 2
// baseline (1242.461 us; speedup 1.0000x reference)
//
#include <hip/hip_runtime.h>
#include <hip/hip_bf16.h>

typedef __attribute__((ext_vector_type(8))) short short8;
typedef __attribute__((ext_vector_type(4))) short shortx4;
typedef __attribute__((ext_vector_type(4))) float floatx4;

// N=128, C=64, T=256, V=25, S=3, RED=4, KER=25, PAD=12
#define NB   128
#define TT   256
#define TW   4
#define X_N  409600
#define X_C  6400

// workspace layout (float offsets)
#define WS_GATE  0        // 204800 floats
#define WS_B2    204800   // 64 floats
#define WS_AFB   204864   // 2560 ushorts (1280 floats)
#define WS_W2B   206144   // 12288 ushorts (6144 floats)
#define WS_PART  212288   // path A: 8192*1600 floats partials; path B: p (204800 floats)

static __device__ __forceinline__ ushort f2b(float f) {
    union { __hip_bfloat16 h; ushort u; } c;
    c.h = __float2bfloat16(f);
    return c.u;
}
static __device__ __forceinline__ float b2f(ushort u) {
    union { ushort u; __hip_bfloat16 h; } c;
    c.u = u;
    return __bfloat162float(c.h);
}

// ---------------- prep: fold BN, build MFMA-fragment-packed weights ----------
__global__ __launch_bounds__(256) void prep_kernel(
    const float* __restrict__ A, const float* __restrict__ PA,
    const float* __restrict__ wd, const float* __restrict__ bd,
    const float* __restrict__ gamma, const float* __restrict__ beta,
    const float* __restrict__ mean, const float* __restrict__ var,
    float* __restrict__ bias2, ushort* __restrict__ Afb, ushort* __restrict__ W2b)
{
    __shared__ float norms[75];
    __shared__ float scs[64];
    int tid = threadIdx.x;
    int gid = blockIdx.x * 256 + tid;
    if (tid < 75) {
        int s = tid / 25, w = tid - s * 25;
        float acc = 0.f;
        for (int i = 0; i < 25; ++i) {
            float v = PA[s * 625 + i * 25 + w];
            acc += v * v;
        }
        norms[tid] = sqrtf(acc) + 1e-4f;   // L2 over rows, per column
    }
    if (tid < 64) {
        float sc = gamma[tid] * rsqrtf(var[tid] + 1e-5f);
        scs[tid] = sc;
        if (blockIdx.x == 0) {
            float bsum = bd[tid] + bd[64 + tid] + bd[128 + tid];
            bias2[tid] = bsum * sc + beta[tid] - mean[tid] * sc;
        }
    }
    __syncthreads();
    // Af B-fragments: B[k=v][n=(s,w)]; rows v>=25 are ZERO (main relies on this)
    for (int i = gid; i < 2560; i += 4096) {
        int j = i & 7; int lane = (i >> 3) & 63; int nt = i >> 9;
        int scol = nt * 16 + (lane & 15);
        int v = ((lane >> 4) & 3) * 8 + j;
        float val = 0.f;
        if (scol < 75 && v < 25) {
            int s = scol / 25, w = scol - s * 25;
            int idx = s * 625 + v * 25 + w;
            val = A[idx] + PA[idx] / norms[s * 25 + w];
        }
        Afb[i] = f2b(val);
    }
    // W2 A-fragments: A[m=o][k=s*64+c] (BN scale folded); [ot][kstep][lane][8]
    for (int i = gid; i < 12288; i += 4096) {
        int j = i & 7; int lane = (i >> 3) & 63; int kq = i >> 9;
        int k = kq % 6; int ot = kq / 6;
        int o = ot * 16 + (lane & 15);
        int kk = k * 32 + ((lane >> 4) & 3) * 8 + j;
        int s = kk >> 6, c = kk & 63;
        W2b[i] = f2b(wd[s * 4096 + o * 64 + c] * scs[o]);
    }
}

// ---------------- main: double-MFMA einsum + BN + residual + ReLU + pool -----
// grid = 128 n x 64 t-tiles(TW=4), 512 threads (8 waves), 3 blocks/CU
template<bool PART>
__global__ __launch_bounds__(512, 6) void main_kernel(
    const float* __restrict__ x, const ushort* __restrict__ Afb,
    const ushort* __restrict__ W2b, const float* __restrict__ bias2,
    float* __restrict__ yout, float* __restrict__ part)
{
    // xs: [t][c][v pad 28] bf16; v=25..27 zeroed, v=28..31 reads spill into next
    // row (finite junk x 0-rows of Af = 0). +8 tail guard for the last row.
    __shared__ ushort xs[4 * 64 * 28 + 8];   // 14352 B
    __shared__ ushort zb[100 * 196];         // z bf16 [col][k pad196] 39200 B | ypf
    float* ypf = (float*)zb;                 // 6400 floats [o][t*25+w]

    int blk = blockIdx.x;
    int n = blk >> 6, tb = blk & 63, t0 = tb * TW;
    int tid = threadIdx.x;
    int w8 = tid >> 6, lane = tid & 63, lm = lane & 15, quad = lane >> 4;
    int ot = w8 & 3, h = w8 >> 2;            // stage2: o-tile, col-half

    // block-invariant fragments (L2-hot)
    short8 bfr[5];
    #pragma unroll
    for (int nt = 0; nt < 5; ++nt)
        bfr[nt] = *(const short8*)(Afb + (nt * 64 + lane) * 8);
    short8 wf[6];
    #pragma unroll
    for (int k = 0; k < 6; ++k)
        wf[k] = *(const short8*)(W2b + ((ot * 6 + k) * 64 + lane) * 8);
    floatx4 bias = *(const floatx4*)(bias2 + ot * 16 + quad * 4);

    // stage 0: x tile -> LDS bf16 (no div/mod in the loop)
    const float* xn = x + (size_t)n * X_N + t0 * 25;
    {
        int c = tid / 100;                   // 0..5 (one div, outside loop)
        int r = tid - c * 100;
        int xoff = c * X_C + r;
        for (int i = tid; i < 6400; i += 512) {
            float xv = xn[xoff];
            int t = (r * 41) >> 10;          // r/25 for r<100
            int v = r - 25 * t;
            xs[(t * 64 + c) * 28 + v] = f2b(xv);
            int nr = r + 12;
            int wr = (nr >= 100) ? 1 : 0;
            r = wr ? nr - 100 : nr;
            c += 5 + wr;
            xoff += wr ? 38312 : 32012;      // 5*6400+12 (+6300 on wrap)
        }
        // zero the 3 pad slots per row + 8-tail guard
        if (tid < 256) {
            int b = tid * 28 + 25;
            xs[b] = 0; xs[b + 1] = 0; xs[b + 2] = 0;
        }
        if (tid < 8) xs[4 * 64 * 28 + tid] = 0;
    }
    __syncthreads();

    // stage 1: z[c][(s,w)] = sum_v x[c][v] Af[v][(s,w)]
    {
        const int t = w8 & 3;
        #pragma unroll
        for (int cj = 0; cj < 2; ++cj) {
            int cm = h * 2 + cj;
            const ushort* ap = &xs[(t * 64 + cm * 16 + lm) * 28 + quad * 8];
            shortx4 a0 = *(const shortx4*)ap;
            shortx4 a1 = *(const shortx4*)(ap + 4);
            short8 av = __builtin_shufflevector(a0, a1, 0, 1, 2, 3, 4, 5, 6, 7);
            #pragma unroll
            for (int nt = 0; nt < 5; ++nt) {
                floatx4 d = __builtin_amdgcn_mfma_f32_16x16x32_bf16(
                    av, bfr[nt], (floatx4)(0.f), 0, 0, 0);
                int scol = nt * 16 + lm;
                if (scol < 75) {
                    int s = scol / 25, w = scol - s * 25;
                    int zcol = t * 25 + w;
                    int krow = s * 64 + cm * 16 + quad * 4;
                    shortx4 sv;
                    sv.x = (short)f2b(d.x); sv.y = (short)f2b(d.y);
                    sv.z = (short)f2b(d.z); sv.w = (short)f2b(d.w);
                    *(shortx4*)(&zb[zcol * 196 + krow]) = sv;
                }
            }
        }
    }
    __syncthreads();

    // stage 2: y[o][(t,w)] = sum_{s,c} W2[o][(s,c)] z[(s,c)][(t,w)]
    floatx4 acc[4];
    int nt0 = h * 4;
    #pragma unroll
    for (int j = 0; j < 4; ++j) acc[j] = bias;
    #pragma unroll
    for (int k = 0; k < 6; ++k) {
        #pragma unroll
        for (int j = 0; j < 4; ++j) {
            int nt = nt0 + j;
            if (nt < 7) {
                int col = nt * 16 + lm;
                const ushort* bp = &zb[col * 196 + k * 32 + quad * 8];
                shortx4 b0 = *(const shortx4*)bp;
                shortx4 b1 = *(const shortx4*)(bp + 4);
                short8 b = __builtin_shufflevector(b0, b1, 0, 1, 2, 3, 4, 5, 6, 7);
                acc[j] = __builtin_amdgcn_mfma_f32_16x16x32_bf16(wf[k], b, acc[j], 0, 0, 0);
            }
        }
    }
    __syncthreads();   // all zb reads done; reuse as ypf

    // scatter acc -> ypf[o][t*25+w]
    int o0 = ot * 16 + quad * 4;
    #pragma unroll
    for (int j = 0; j < 4; ++j) {
        int nt = nt0 + j;
        if (nt < 7) {
            int col = nt * 16 + lm;
            if (col < 100) {
                #pragma unroll
                for (int r = 0; r < 4; ++r)
                    ypf[(o0 + r) * 100 + col] = acc[j][r];
            }
        }
    }
    __syncthreads();

    // finalize: +residual, ReLU, coalesced store (no div/mod in the loop)
    size_t ybase = (size_t)n * X_N + (size_t)tb * 100;
    {
        int o = tid / 100;
        int rr = tid - o * 100;
        int yoff = o * X_C + rr;
        for (int j = tid; j < 6400; j += 512) {
            int t = (rr * 41) >> 10;
            int w = rr - 25 * t;
            float v = ypf[j] + b2f(xs[(t * 64 + o) * 28 + w]);
            v = fmaxf(v, 0.f);
            yout[ybase + yoff] = v;
            if (PART) ypf[j] = v;
            int nr = rr + 12;
            int wr = (nr >= 100) ? 1 : 0;
            rr = wr ? nr - 100 : nr;
            o += 5 + wr;
            yoff += wr ? 38312 : 32012;
        }
    }
    if (PART) {
        __syncthreads();
        for (int i = tid; i < 1600; i += 512) {
            int o = i / 25, w = i - o * 25;
            const float* yp = &ypf[o * 100 + w];
            part[(size_t)blk * 1600 + i] = yp[0] + yp[25] + yp[50] + yp[75];
        }
    }
}

// ---------------- path-B pool: p[n][o][w] = sum_t y ----------------
__global__ __launch_bounds__(256) void pool_kernel(
    const float* __restrict__ y, float* __restrict__ p)
{
    __shared__ float red[8][25];
    int no = blockIdx.x;            // n*64 + o
    int tid = threadIdx.x;
    if (tid < 200) {
        int tg = tid / 25, w = tid - tg * 25;
        const float* yp = y + (size_t)no * 6400 + w;
        float s = 0.f;
        for (int t = tg * 32; t < tg * 32 + 32; ++t) s += yp[t * 25];
        red[tg][w] = s;
    }
    __syncthreads();
    if (tid < 25) {
        float s = 0.f;
        #pragma unroll
        for (int g = 0; g < 8; ++g) s += red[g][tid];
        p[(size_t)no * 25 + tid] = s;
    }
}

// ---------------- SCE gate ----------------
// FROMPART: pp = part[n][64][1600], reduce in registers (coalesced).
// else:     pp = p[n][1600] (t-sums).
template<bool FROMPART>
__global__ __launch_bounds__(256) void sce_kernel(
    const float* __restrict__ pp, const float* __restrict__ sws,
    const float* __restrict__ sbs, const float* __restrict__ swe,
    const float* __restrict__ sbe, float* __restrict__ gate)
{
    __shared__ float pm[1600];
    __shared__ float wss[6400];
    __shared__ float sq[100];
    int n = blockIdx.x, tid = threadIdx.x;
    if (FROMPART) {
        float s0 = 0.f, s1 = 0.f, s2 = 0.f, s3 = 0.f, s4 = 0.f, s5 = 0.f, s6 = 0.f;
        const float* q = pp + (size_t)n * 102400;
        for (int tb = 0; tb < 64; ++tb) {
            const float* qt = q + tb * 1600;
            s0 += qt[tid];
            s1 += qt[tid + 256];
            s2 += qt[tid + 512];
            s3 += qt[tid + 768];
            s4 += qt[tid + 1024];
            s5 += qt[tid + 1280];
            if (tid < 64) s6 += qt[tid + 1536];
        }
        pm[tid]        = s0 * (1.f / 256.f);
        pm[tid + 256]  = s1 * (1.f / 256.f);
        pm[tid + 512]  = s2 * (1.f / 256.f);
        pm[tid + 768]  = s3 * (1.f / 256.f);
        pm[tid + 1024] = s4 * (1.f / 256.f);
        pm[tid + 1280] = s5 * (1.f / 256.f);
        if (tid < 64) pm[tid + 1536] = s6 * (1.f / 256.f);
    } else {
        for (int i = tid; i < 1600; i += 256)
            pm[i] = pp[(size_t)n * 1600 + i] * (1.f / 256.f);
    }
    for (int i = tid; i < 6400; i += 256) wss[i] = sws[i];
    __syncthreads();
    if (tid < 100) {
        int r = tid / 25, w = tid - (tid / 25) * 25;
        float acc = sbs[r];
        for (int o = 0; o < 64; ++o) {
            const float* wr = &wss[(r * 64 + o) * 25];
            const float* pr = &pm[o * 25];
            int k0 = (w < 12) ? 12 - w : 0;
            int k1 = (w > 12) ? 37 - w : 25;
            for (int k = k0; k < k1; ++k) acc += pr[w + k - 12] * wr[k];
        }
        sq[tid] = fmaxf(acc, 0.f);
    }
    __syncthreads();
    for (int i = tid; i < 1600; i += 256) {
        int o = i / 25, w = i - (i / 25) * 25;
        float acc = sbe[o];
        #pragma unroll
        for (int r = 0; r < 4; ++r) acc += sq[r * 25 + w] * swe[o * 4 + r];
        gate[(size_t)n * 1600 + i] = 1.f + 1.f / (1.f + __expf(-acc));
    }
}

// ---------------- final gated multiply (in-place on d_out) ----------------
// one block per (n,o) row of 6400 floats; gate row expanded to g100[r]=g[r%25]
__global__ __launch_bounds__(320) void gate_mul_kernel(
    float* __restrict__ y, const float* __restrict__ gate)
{
    __shared__ float g100[100];
    int no = blockIdx.x;                 // n*64 + o
    int tid = threadIdx.x;
    if (tid < 100) {
        int w = tid % 25;
        g100[tid] = gate[(no >> 6) * 1600 + (no & 63) * 25 + w];
    }
    __syncthreads();
    float4* yp = (float4*)(y + (size_t)no * 6400);
    #pragma unroll
    for (int it = 0; it < 5; ++it) {
        int j4 = tid + it * 320;         // 0..1599 float4s
        float4 v = yp[j4];
        int idx = j4 % 25;               // rr%100 == 4*idx
        float4 gv = *(const float4*)&g100[4 * idx];
        v.x *= gv.x; v.y *= gv.y; v.z *= gv.z; v.w *= gv.w;
        yp[j4] = v;
    }
}

extern "C" void kernel_launch(void* const* d_in, const int* in_sizes, int n_in,
                              void* d_out, int out_size, void* d_ws, size_t ws_size,
                              hipStream_t stream) {
    const float* x     = (const float*)d_in[0];
    const float* A     = (const float*)d_in[1];
    const float* PA    = (const float*)d_in[2];
    const float* wd    = (const float*)d_in[3];
    const float* bd    = (const float*)d_in[4];
    const float* gamma = (const float*)d_in[5];
    const float* beta  = (const float*)d_in[6];
    const float* mean  = (const float*)d_in[7];
    const float* var   = (const float*)d_in[8];
    const float* sws   = (const float*)d_in[9];
    const float* sbs   = (const float*)d_in[10];
    const float* swe   = (const float*)d_in[11];
    const float* sbe   = (const float*)d_in[12];

    float* out   = (float*)d_out;
    float* ws    = (float*)d_ws;
    float* gate  = ws + WS_GATE;
    float* bias2 = ws + WS_B2;
    ushort* Afb  = (ushort*)(ws + WS_AFB);
    ushort* W2b  = (ushort*)(ws + WS_W2B);
    float* part  = ws + WS_PART;

    // partials need 8192*1600 floats beyond WS_PART
    bool useA = ws_size >= ((size_t)WS_PART + (size_t)8192 * 1600) * 4;

    prep_kernel<<<16, 256, 0, stream>>>(A, PA, wd, bd, gamma, beta, mean, var,
                                        bias2, Afb, W2b);
    if (useA) {
        main_kernel<true><<<NB * (TT / TW), 512, 0, stream>>>(x, Afb, W2b, bias2, out, part);
        sce_kernel<true><<<NB, 256, 0, stream>>>(part, sws, sbs, swe, sbe, gate);
    } else {
        main_kernel<false><<<NB * (TT / TW), 512, 0, stream>>>(x, Afb, W2b, bias2, out, part);
        pool_kernel<<<NB * 64, 256, 0, stream>>>(out, part);
        sce_kernel<false><<<NB, 256, 0, stream>>>(part, sws, sbs, swe, sbe, gate);
    }
    gate_mul_kernel<<<NB * 64, 320, 0, stream>>>(out, gate);
}

// Round 4
// 736.014 us; speedup vs baseline: 1.6881x; 1.6881x over previous
//
#include <hip/hip_runtime.h>
#include <hip/hip_bf16.h>

typedef __attribute__((ext_vector_type(8))) short short8;
typedef __attribute__((ext_vector_type(4))) short shortx4;
typedef __attribute__((ext_vector_type(4))) float floatx4;

// N=128, C=64, T=256, V=25, S=3, RED=4, KER=25, PAD=12
#define NB   128
#define TT   256
#define TW   4
#define X_N  409600
#define X_C  6400

// workspace layout (float offsets)
#define WS_GATE  0        // 204800 floats
#define WS_B2    204800   // 64 floats
#define WS_AFB   204864   // 2560 ushorts (1280 floats)
#define WS_W2B   206144   // 12288 ushorts (6144 floats)
#define WS_PART  212288   // path A: 8192*1600 floats partials; path B: p (204800 floats)

static __device__ __forceinline__ ushort f2b(float f) {
    union { __hip_bfloat16 h; ushort u; } c;
    c.h = __float2bfloat16(f);
    return c.u;
}
static __device__ __forceinline__ float b2f(ushort u) {
    union { ushort u; __hip_bfloat16 h; } c;
    c.u = u;
    return __bfloat162float(c.h);
}

// ---------------- prep: fold BN, build MFMA-fragment-packed weights ----------
__global__ __launch_bounds__(256) void prep_kernel(
    const float* __restrict__ A, const float* __restrict__ PA,
    const float* __restrict__ wd, const float* __restrict__ bd,
    const float* __restrict__ gamma, const float* __restrict__ beta,
    const float* __restrict__ mean, const float* __restrict__ var,
    float* __restrict__ bias2, ushort* __restrict__ Afb, ushort* __restrict__ W2b)
{
    __shared__ float norms[75];
    __shared__ float scs[64];
    int tid = threadIdx.x;
    int gid = blockIdx.x * 256 + tid;
    if (tid < 75) {
        int s = tid / 25, w = tid - s * 25;
        float acc = 0.f;
        for (int i = 0; i < 25; ++i) {
            float v = PA[s * 625 + i * 25 + w];
            acc += v * v;
        }
        norms[tid] = sqrtf(acc) + 1e-4f;   // L2 over rows, per column
    }
    if (tid < 64) {
        float sc = gamma[tid] * rsqrtf(var[tid] + 1e-5f);
        scs[tid] = sc;
        if (blockIdx.x == 0) {
            float bsum = bd[tid] + bd[64 + tid] + bd[128 + tid];
            bias2[tid] = bsum * sc + beta[tid] - mean[tid] * sc;
        }
    }
    __syncthreads();
    // Af B-fragments: B[k=v][n=(s,w)]; rows v>=25 are ZERO (main relies on this)
    for (int i = gid; i < 2560; i += 4096) {
        int j = i & 7; int lane = (i >> 3) & 63; int nt = i >> 9;
        int scol = nt * 16 + (lane & 15);
        int v = ((lane >> 4) & 3) * 8 + j;
        float val = 0.f;
        if (scol < 75 && v < 25) {
            int s = scol / 25, w = scol - s * 25;
            int idx = s * 625 + v * 25 + w;
            val = A[idx] + PA[idx] / norms[s * 25 + w];
        }
        Afb[i] = f2b(val);
    }
    // W2 A-fragments: A[m=o][k=s*64+c] (BN scale folded); [ot][kstep][lane][8]
    for (int i = gid; i < 12288; i += 4096) {
        int j = i & 7; int lane = (i >> 3) & 63; int kq = i >> 9;
        int k = kq % 6; int ot = kq / 6;
        int o = ot * 16 + (lane & 15);
        int kk = k * 32 + ((lane >> 4) & 3) * 8 + j;
        int s = kk >> 6, c = kk & 63;
        W2b[i] = f2b(wd[s * 4096 + o * 64 + c] * scs[o]);
    }
}

// ---------------- main: double-MFMA einsum + BN + residual + ReLU + pool -----
// grid = 128 n x 64 t-tiles(TW=4), 512 threads (8 waves)
// LDS 53.7 KB -> 3 blocks/CU; launch_bounds(512,4) keeps VGPR=56 (NO spill —
// (512,6) forced VGPR=40 and spilled the MFMA fragments to scratch: +1GB HBM).
template<bool PART>
__global__ __launch_bounds__(512, 4) void main_kernel(
    const float* __restrict__ x, const ushort* __restrict__ Afb,
    const ushort* __restrict__ W2b, const float* __restrict__ bias2,
    float* __restrict__ yout, float* __restrict__ part)
{
    // xs: [t][c][v pad 28] bf16; v=25..27 zeroed, v=28..31 reads spill into next
    // row (finite junk x 0-rows of Af = 0). +8 tail guard for the last row.
    __shared__ ushort xs[4 * 64 * 28 + 8];   // 14352 B
    __shared__ ushort zb[100 * 196];         // z bf16 [col][k pad196] 39200 B | ypf
    float* ypf = (float*)zb;                 // 6400 floats [o][t*25+w]

    int blk = blockIdx.x;
    int n = blk >> 6, tb = blk & 63, t0 = tb * TW;
    int tid = threadIdx.x;
    int w8 = tid >> 6, lane = tid & 63, lm = lane & 15, quad = lane >> 4;
    int ot = w8 & 3, h = w8 >> 2;            // stage2: o-tile, col-half

    // block-invariant fragments (L2-hot)
    short8 bfr[5];
    #pragma unroll
    for (int nt = 0; nt < 5; ++nt)
        bfr[nt] = *(const short8*)(Afb + (nt * 64 + lane) * 8);
    short8 wf[6];
    #pragma unroll
    for (int k = 0; k < 6; ++k)
        wf[k] = *(const short8*)(W2b + ((ot * 6 + k) * 64 + lane) * 8);
    floatx4 bias = *(const floatx4*)(bias2 + ot * 16 + quad * 4);

    // stage 0: x tile -> LDS bf16 (no div/mod in the loop)
    const float* xn = x + (size_t)n * X_N + t0 * 25;
    {
        int c = tid / 100;                   // 0..5 (one div, outside loop)
        int r = tid - c * 100;
        int xoff = c * X_C + r;
        for (int i = tid; i < 6400; i += 512) {
            float xv = xn[xoff];
            int t = (r * 41) >> 10;          // r/25 for r<100
            int v = r - 25 * t;
            xs[(t * 64 + c) * 28 + v] = f2b(xv);
            int nr = r + 12;
            int wr = (nr >= 100) ? 1 : 0;
            r = wr ? nr - 100 : nr;
            c += 5 + wr;
            xoff += wr ? 38312 : 32012;      // 5*6400+12 (+6300 on wrap)
        }
        // zero the 3 pad slots per row + 8-tail guard
        if (tid < 256) {
            int b = tid * 28 + 25;
            xs[b] = 0; xs[b + 1] = 0; xs[b + 2] = 0;
        }
        if (tid < 8) xs[4 * 64 * 28 + tid] = 0;
    }
    __syncthreads();

    // stage 1: z[c][(s,w)] = sum_v x[c][v] Af[v][(s,w)]
    {
        const int t = w8 & 3;
        #pragma unroll
        for (int cj = 0; cj < 2; ++cj) {
            int cm = h * 2 + cj;
            const ushort* ap = &xs[(t * 64 + cm * 16 + lm) * 28 + quad * 8];
            shortx4 a0 = *(const shortx4*)ap;
            shortx4 a1 = *(const shortx4*)(ap + 4);
            short8 av = __builtin_shufflevector(a0, a1, 0, 1, 2, 3, 4, 5, 6, 7);
            #pragma unroll
            for (int nt = 0; nt < 5; ++nt) {
                floatx4 d = __builtin_amdgcn_mfma_f32_16x16x32_bf16(
                    av, bfr[nt], (floatx4)(0.f), 0, 0, 0);
                int scol = nt * 16 + lm;
                if (scol < 75) {
                    int s = scol / 25, w = scol - s * 25;
                    int zcol = t * 25 + w;
                    int krow = s * 64 + cm * 16 + quad * 4;
                    shortx4 sv;
                    sv.x = (short)f2b(d.x); sv.y = (short)f2b(d.y);
                    sv.z = (short)f2b(d.z); sv.w = (short)f2b(d.w);
                    *(shortx4*)(&zb[zcol * 196 + krow]) = sv;
                }
            }
        }
    }
    __syncthreads();

    // stage 2: y[o][(t,w)] = sum_{s,c} W2[o][(s,c)] z[(s,c)][(t,w)]
    floatx4 acc[4];
    int nt0 = h * 4;
    #pragma unroll
    for (int j = 0; j < 4; ++j) acc[j] = bias;
    #pragma unroll
    for (int k = 0; k < 6; ++k) {
        #pragma unroll
        for (int j = 0; j < 4; ++j) {
            int nt = nt0 + j;
            if (nt < 7) {
                int col = nt * 16 + lm;
                const ushort* bp = &zb[col * 196 + k * 32 + quad * 8];
                shortx4 b0 = *(const shortx4*)bp;
                shortx4 b1 = *(const shortx4*)(bp + 4);
                short8 b = __builtin_shufflevector(b0, b1, 0, 1, 2, 3, 4, 5, 6, 7);
                acc[j] = __builtin_amdgcn_mfma_f32_16x16x32_bf16(wf[k], b, acc[j], 0, 0, 0);
            }
        }
    }
    __syncthreads();   // all zb reads done; reuse as ypf

    // scatter acc -> ypf[o][t*25+w]
    int o0 = ot * 16 + quad * 4;
    #pragma unroll
    for (int j = 0; j < 4; ++j) {
        int nt = nt0 + j;
        if (nt < 7) {
            int col = nt * 16 + lm;
            if (col < 100) {
                #pragma unroll
                for (int r = 0; r < 4; ++r)
                    ypf[(o0 + r) * 100 + col] = acc[j][r];
            }
        }
    }
    __syncthreads();

    // finalize: +residual, ReLU, coalesced store (no div/mod in the loop)
    size_t ybase = (size_t)n * X_N + (size_t)tb * 100;
    {
        int o = tid / 100;
        int rr = tid - o * 100;
        int yoff = o * X_C + rr;
        for (int j = tid; j < 6400; j += 512) {
            int t = (rr * 41) >> 10;
            int w = rr - 25 * t;
            float v = ypf[j] + b2f(xs[(t * 64 + o) * 28 + w]);
            v = fmaxf(v, 0.f);
            yout[ybase + yoff] = v;
            if (PART) ypf[j] = v;
            int nr = rr + 12;
            int wr = (nr >= 100) ? 1 : 0;
            rr = wr ? nr - 100 : nr;
            o += 5 + wr;
            yoff += wr ? 38312 : 32012;
        }
    }
    if (PART) {
        __syncthreads();
        for (int i = tid; i < 1600; i += 512) {
            int o = i / 25, w = i - o * 25;
            const float* yp = &ypf[o * 100 + w];
            part[(size_t)blk * 1600 + i] = yp[0] + yp[25] + yp[50] + yp[75];
        }
    }
}

// ---------------- path-B pool: p[n][o][w] = sum_t y ----------------
__global__ __launch_bounds__(256) void pool_kernel(
    const float* __restrict__ y, float* __restrict__ p)
{
    __shared__ float red[8][25];
    int no = blockIdx.x;            // n*64 + o
    int tid = threadIdx.x;
    if (tid < 200) {
        int tg = tid / 25, w = tid - tg * 25;
        const float* yp = y + (size_t)no * 6400 + w;
        float s = 0.f;
        for (int t = tg * 32; t < tg * 32 + 32; ++t) s += yp[t * 25];
        red[tg][w] = s;
    }
    __syncthreads();
    if (tid < 25) {
        float s = 0.f;
        #pragma unroll
        for (int g = 0; g < 8; ++g) s += red[g][tid];
        p[(size_t)no * 25 + tid] = s;
    }
}

// ---------------- SCE gate ----------------
// FROMPART: pp = part[n][64][1600], reduce in registers (coalesced).
// else:     pp = p[n][1600] (t-sums).
template<bool FROMPART>
__global__ __launch_bounds__(256) void sce_kernel(
    const float* __restrict__ pp, const float* __restrict__ sws,
    const float* __restrict__ sbs, const float* __restrict__ swe,
    const float* __restrict__ sbe, float* __restrict__ gate)
{
    __shared__ float pm[1600];
    __shared__ float wss[6400];
    __shared__ float sq[100];
    int n = blockIdx.x, tid = threadIdx.x;
    if (FROMPART) {
        float s0 = 0.f, s1 = 0.f, s2 = 0.f, s3 = 0.f, s4 = 0.f, s5 = 0.f, s6 = 0.f;
        const float* q = pp + (size_t)n * 102400;
        for (int tb = 0; tb < 64; ++tb) {
            const float* qt = q + tb * 1600;
            s0 += qt[tid];
            s1 += qt[tid + 256];
            s2 += qt[tid + 512];
            s3 += qt[tid + 768];
            s4 += qt[tid + 1024];
            s5 += qt[tid + 1280];
            if (tid < 64) s6 += qt[tid + 1536];
        }
        pm[tid]        = s0 * (1.f / 256.f);
        pm[tid + 256]  = s1 * (1.f / 256.f);
        pm[tid + 512]  = s2 * (1.f / 256.f);
        pm[tid + 768]  = s3 * (1.f / 256.f);
        pm[tid + 1024] = s4 * (1.f / 256.f);
        pm[tid + 1280] = s5 * (1.f / 256.f);
        if (tid < 64) pm[tid + 1536] = s6 * (1.f / 256.f);
    } else {
        for (int i = tid; i < 1600; i += 256)
            pm[i] = pp[(size_t)n * 1600 + i] * (1.f / 256.f);
    }
    for (int i = tid; i < 6400; i += 256) wss[i] = sws[i];
    __syncthreads();
    if (tid < 100) {
        int r = tid / 25, w = tid - (tid / 25) * 25;
        float acc = sbs[r];
        for (int o = 0; o < 64; ++o) {
            const float* wr = &wss[(r * 64 + o) * 25];
            const float* pr = &pm[o * 25];
            int k0 = (w < 12) ? 12 - w : 0;
            int k1 = (w > 12) ? 37 - w : 25;
            for (int k = k0; k < k1; ++k) acc += pr[w + k - 12] * wr[k];
        }
        sq[tid] = fmaxf(acc, 0.f);
    }
    __syncthreads();
    for (int i = tid; i < 1600; i += 256) {
        int o = i / 25, w = i - (i / 25) * 25;
        float acc = sbe[o];
        #pragma unroll
        for (int r = 0; r < 4; ++r) acc += sq[r * 25 + w] * swe[o * 4 + r];
        gate[(size_t)n * 1600 + i] = 1.f + 1.f / (1.f + __expf(-acc));
    }
}

// ---------------- final gated multiply (in-place on d_out) ----------------
// one block per (n,o) row of 6400 floats; gate row expanded to g100[r]=g[r%25]
__global__ __launch_bounds__(320) void gate_mul_kernel(
    float* __restrict__ y, const float* __restrict__ gate)
{
    __shared__ float g100[100];
    int no = blockIdx.x;                 // n*64 + o
    int tid = threadIdx.x;
    if (tid < 100) {
        int w = tid % 25;
        g100[tid] = gate[(no >> 6) * 1600 + (no & 63) * 25 + w];
    }
    __syncthreads();
    float4* yp = (float4*)(y + (size_t)no * 6400);
    #pragma unroll
    for (int it = 0; it < 5; ++it) {
        int j4 = tid + it * 320;         // 0..1599 float4s
        float4 v = yp[j4];
        int idx = j4 % 25;               // rr%100 == 4*idx
        float4 gv = *(const float4*)&g100[4 * idx];
        v.x *= gv.x; v.y *= gv.y; v.z *= gv.z; v.w *= gv.w;
        yp[j4] = v;
    }
}

extern "C" void kernel_launch(void* const* d_in, const int* in_sizes, int n_in,
                              void* d_out, int out_size, void* d_ws, size_t ws_size,
                              hipStream_t stream) {
    const float* x     = (const float*)d_in[0];
    const float* A     = (const float*)d_in[1];
    const float* PA    = (const float*)d_in[2];
    const float* wd    = (const float*)d_in[3];
    const float* bd    = (const float*)d_in[4];
    const float* gamma = (const float*)d_in[5];
    const float* beta  = (const float*)d_in[6];
    const float* mean  = (const float*)d_in[7];
    const float* var   = (const float*)d_in[8];
    const float* sws   = (const float*)d_in[9];
    const float* sbs   = (const float*)d_in[10];
    const float* swe   = (const float*)d_in[11];
    const float* sbe   = (const float*)d_in[12];

    float* out   = (float*)d_out;
    float* ws    = (float*)d_ws;
    float* gate  = ws + WS_GATE;
    float* bias2 = ws + WS_B2;
    ushort* Afb  = (ushort*)(ws + WS_AFB);
    ushort* W2b  = (ushort*)(ws + WS_W2B);
    float* part  = ws + WS_PART;

    // partials need 8192*1600 floats beyond WS_PART
    bool useA = ws_size >= ((size_t)WS_PART + (size_t)8192 * 1600) * 4;

    prep_kernel<<<16, 256, 0, stream>>>(A, PA, wd, bd, gamma, beta, mean, var,
                                        bias2, Afb, W2b);
    if (useA) {
        main_kernel<true><<<NB * (TT / TW), 512, 0, stream>>>(x, Afb, W2b, bias2, out, part);
        sce_kernel<true><<<NB, 256, 0, stream>>>(part, sws, sbs, swe, sbe, gate);
    } else {
        main_kernel<false><<<NB * (TT / TW), 512, 0, stream>>>(x, Afb, W2b, bias2, out, part);
        pool_kernel<<<NB * 64, 256, 0, stream>>>(out, part);
        sce_kernel<false><<<NB, 256, 0, stream>>>(part, sws, sbs, swe, sbe, gate);
    }
    gate_mul_kernel<<<NB * 64, 320, 0, stream>>>(out, gate);
}